// Round 9
// baseline (109.006 us; speedup 1.0000x reference)
//
#include <hip/hip_runtime.h>
#include <math.h>

#define BATCH 32
#define TH    256
#define TQn   64
#define DIN   256
#define DD    256   // INTERNAL
#define QT    4     // q's per attn block (R9: back to 4; R8 QT=8 regressed)
#define E2C   2.885390081777927f   // 2*log2(e): exp(2x) == exp2(x*E2C)
#define NL2E  -2.8853900817779268f // -2*log2(e) for unshifted softmax exp2

typedef __attribute__((ext_vector_type(8)))  short bf16x8;   // 8 bf16 = 4 VGPRs
typedef __attribute__((ext_vector_type(16))) float floatx16;
typedef __attribute__((ext_vector_type(4)))  float f32x4;

// exp2(E2C*x) clamped to 2^30: den=1+P*K <= 2^60+1, pair product d0*d1 <= 2^121
// finite without per-element clamps. Clamp engages only at |proj| > 10.4 sigma.
__device__ __forceinline__ float eclamp(float x) {
    return __builtin_amdgcn_exp2f(fminf(x * E2C, 30.f));
}

// 2-term bf16 expansion of two floats, packed as (e0 low half | e1 high half).
__device__ __forceinline__ void split2(float x0, float x1, unsigned& hi, unsigned& lo) {
    unsigned u0 = __float_as_uint(x0), u1 = __float_as_uint(x1);
    unsigned h0 = u0 & 0xFFFF0000u,   h1 = u1 & 0xFFFF0000u;
    float r0 = x0 - __uint_as_float(h0);
    float r1 = x1 - __uint_as_float(h1);
    hi = (u0 >> 16) | h1;
    lo = (__float_as_uint(r0) >> 16) | (__float_as_uint(r1) & 0xFFFF0000u);
}

__device__ __forceinline__ void split8(float4 f0, float4 f1, uint4& hi, uint4& lo) {
    split2(f0.x, f0.y, hi.x, lo.x);
    split2(f0.z, f0.w, hi.y, lo.y);
    split2(f1.x, f1.y, hi.z, lo.z);
    split2(f1.z, f1.w, hi.w, lo.w);
}

// ---------------------------------------------------------------------------
// Kernel 1: projections via bf16-split MFMA (3x mfma_f32_32x32x16_bf16).
// Epilogue stores exp2c(proj):
//   Ktp packed: Ktp[b][d>>2][t][d&3]  (LDS transpose; attn reads dwordx4)
//   Pq[r][d]   (row-major; attn reads via uniform s_load)
// ---------------------------------------------------------------------------
#define REG4  65                    // uint4 per region (64 + 1 pad)
#define WOFF  (16 * REG4)           // W base in uint4 units
#define TSTR  68                    // transpose LDS stride (17*16B rows)
__global__ __launch_bounds__(256, 4)
void proj_kernel(const float* __restrict__ keys,
                 const float* __restrict__ state,
                 const float* __restrict__ w1,
                 const float* __restrict__ w2,
                 float* __restrict__ ktp,
                 float* __restrict__ qpo)
{
    __shared__ uint4 lds4[2 * 16 * REG4];   // 32.5 KB (reused for transpose)

    const int bid = blockIdx.x;
    const int tid = threadIdx.x;

    const float* X;
    const float* W;
    int m0, n0;
    bool is_kp;
    if (bid < 512) {
        is_kp = true;
        m0 = (bid >> 2) * 64;
        n0 = (bid & 3) * 64;
        X = keys; W = w1;
    } else {
        is_kp = false;
        int lb = bid - 512;
        m0 = (lb >> 2) * 64;
        n0 = (lb & 3) * 64;
        X = state; W = w2;
    }

    const int w    = tid >> 6;        // wave 0..3
    const int l    = tid & 63;
    const int mt   = w >> 1;          // m half-tile
    const int nt   = w & 1;           // n half-tile
    const int srow = tid >> 3;        // 0..31
    const int kg   = tid & 7;         // 0..7
    const int s_s  = kg >> 1;         // k-step 0..3
    const int lidx = (srow & 31) + 32 * (kg & 1);

    floatx16 acc = {};

    for (int k0 = 0; k0 < DIN; k0 += 64) {
        #pragma unroll
        for (int hrow = 0; hrow < 2; hrow++) {
            int m = srow + hrow * 32;
            const float* px = X + (size_t)(m0 + m) * DIN + k0 + kg * 8;
            uint4 hi, lo;
            split8(*(const float4*)px, *(const float4*)(px + 4), hi, lo);
            int g = m >> 5;
            lds4[((0 * 2 + g) * 4 + s_s) * REG4 + lidx] = hi;
            lds4[((2 + g) * 4 + s_s) * REG4 + lidx] = lo;
            const float* pw = W + (size_t)(n0 + m) * DIN + k0 + kg * 8;
            split8(*(const float4*)pw, *(const float4*)(pw + 4), hi, lo);
            lds4[WOFF + ((0 * 2 + g) * 4 + s_s) * REG4 + lidx] = hi;
            lds4[WOFF + ((2 + g) * 4 + s_s) * REG4 + lidx] = lo;
        }
        __syncthreads();

        #pragma unroll
        for (int s = 0; s < 4; s++) {
            uint4 ahr = lds4[((0 * 2 + mt) * 4 + s) * REG4 + l];
            uint4 alr = lds4[((2 + mt) * 4 + s) * REG4 + l];
            uint4 bhr = lds4[WOFF + ((0 * 2 + nt) * 4 + s) * REG4 + l];
            uint4 blr = lds4[WOFF + ((2 + nt) * 4 + s) * REG4 + l];
            bf16x8 ah = __builtin_bit_cast(bf16x8, ahr);
            bf16x8 al = __builtin_bit_cast(bf16x8, alr);
            bf16x8 bh = __builtin_bit_cast(bf16x8, bhr);
            bf16x8 bl = __builtin_bit_cast(bf16x8, blr);
            acc = __builtin_amdgcn_mfma_f32_32x32x16_bf16(ah, bh, acc, 0, 0, 0);
            acc = __builtin_amdgcn_mfma_f32_32x32x16_bf16(al, bh, acc, 0, 0, 0);
            acc = __builtin_amdgcn_mfma_f32_32x32x16_bf16(ah, bl, acc, 0, 0, 0);
        }
        __syncthreads();
    }

    // C/D map: col=l&31 (n=d), row=(r&3)+8*(r>>2)+4*(l>>5) (m=t/row)
    const int col = l & 31;
    const int hl  = l >> 5;
    if (is_kp) {
        // ---- transpose tile through LDS to d-packed layout ----
        float* sT = (float*)lds4;            // sT[t_local][d_local], stride TSTR
        const int d_local = nt * 32 + col;
        #pragma unroll
        for (int r = 0; r < 16; r++) {
            int t_local = mt * 32 + 4 * hl + 8 * (r >> 2) + (r & 3);
            sT[t_local * TSTR + d_local] = eclamp(acc[r]);
        }
        __syncthreads();
        const int b  = m0 >> 8;
        const int t0 = m0 & 255;
        float4* dst4 = (float4*)ktp;
        #pragma unroll
        for (int p = 0; p < 4; p++) {
            int dp_local = w * 4 + p;                 // 0..15
            float4 v4 = *(float4*)&sT[l * TSTR + dp_local * 4];
            dst4[(size_t)(b * 64 + (n0 >> 2) + dp_local) * 256 + t0 + l] = v4;
        }
    } else {
        const int d = n0 + nt * 32 + col;
        #pragma unroll
        for (int r = 0; r < 16; r++) {
            int row = (r & 3) + 8 * (r >> 2) + 4 * hl;
            qpo[(size_t)(m0 + mt * 32 + row) * DD + d] = eclamp(acc[r]);
        }
    }
}

// ---------------------------------------------------------------------------
// Kernel 2: fused scores + softmax + context. 1024 threads, grid 512, QT=4.
// R9: __launch_bounds__(1024,4) -> VGPR cap 128 (was 64, compiler allocated
// 16-28 -> ~1 load in flight -> latency-serialized). Score loads ALL 16 kv
// quads up-front (64 VGPRs in flight, single wait, then pure math).
// Score: T(q,t) = sum_d v_d / (1 + Pq[q,d]*Kt[d,t]); softmax input = -2T;
//   pair-combine rational (1 rcp / 2 d); Pq/v via uniform s_load.
// Softmax without max-shift (|score| <= 2*sum|v| ~ 26, fp32-safe).
// Context: thread = (i-quad il, t-chunk tl of 16 contiguous t's); alphas
//   register-blocked via 4x ds_read_b128 per q; pure f32x4 FMA inner loop.
// ---------------------------------------------------------------------------
__global__ __launch_bounds__(1024, 4)
void attn_kernel(const float* __restrict__ keys,
                 const float* __restrict__ vvec,
                 const float* __restrict__ ktp,
                 const float* __restrict__ qp,
                 float* __restrict__ out)
{
    __shared__ float s_part[4][QT][TH];   // 16 KB: score partials, then ctx partials
    __shared__ float s_alpha[QT][TH];     // 4 KB
    __shared__ float s_rsum[QT];

    const int bid  = blockIdx.x;          // 0..511
    const int b    = bid & 31;            // bid%8 == b%8 -> XCD-local batch
    const int q0   = (bid >> 5) * QT;
    const int tid  = threadIdx.x;
    const int t    = tid & 255;
    const int dgu  = __builtin_amdgcn_readfirstlane(tid >> 8);  // quarter, uniform
    const int lane = tid & 63;
    const int wv   = tid >> 6;

    // ---- scores (this quarter's 64 d's = 16 packed quads) ----
    float acc[QT];
    #pragma unroll
    for (int q = 0; q < QT; q++) acc[q] = 0.f;

    const float4* kb4 = (const float4*)ktp + ((size_t)(b * 64 + dgu * 16) * 256 + t);
    const float*  pqb = qp + (size_t)(b * TQn + q0) * DD + dgu * 64;  // uniform base
    const float*  vvp = vvec + dgu * 64;                              // uniform base

    // load ALL 16 kv quads first: 16 dwordx4 in flight, one wait, pure math after
    float4 kvv[16];
    #pragma unroll
    for (int dp = 0; dp < 16; dp++) kvv[dp] = kb4[(size_t)dp * 256];

    #pragma unroll
    for (int dp = 0; dp < 16; dp++) {
        const float4 kv = kvv[dp];
        const float v0 = vvp[dp * 4 + 0], v1 = vvp[dp * 4 + 1];
        const float v2 = vvp[dp * 4 + 2], v3 = vvp[dp * 4 + 3];
        #pragma unroll
        for (int q = 0; q < QT; q++) {
            const float* pr = pqb + q * DD + dp * 4;   // uniform, imm offsets
            float d0 = fmaf(pr[0], kv.x, 1.f);
            float d1 = fmaf(pr[1], kv.y, 1.f);
            float n01 = fmaf(v1, d0, v0 * d1);
            acc[q] = fmaf(n01, __builtin_amdgcn_rcpf(d0 * d1), acc[q]);
            float d2 = fmaf(pr[2], kv.z, 1.f);
            float d3 = fmaf(pr[3], kv.w, 1.f);
            float n23 = fmaf(v3, d2, v2 * d3);
            acc[q] = fmaf(n23, __builtin_amdgcn_rcpf(d2 * d3), acc[q]);
        }
    }

    #pragma unroll
    for (int q = 0; q < QT; q++) s_part[dgu][q][t] = acc[q];
    __syncthreads();

    // ---- softmax over t=256 (no max shift); wave wv (<QT) handles q=wv ----
    if (wv < QT) {
        const int q = wv;
        float p0 = s_part[0][q][lane]       + s_part[1][q][lane]
                 + s_part[2][q][lane]       + s_part[3][q][lane];
        float p1 = s_part[0][q][lane + 64]  + s_part[1][q][lane + 64]
                 + s_part[2][q][lane + 64]  + s_part[3][q][lane + 64];
        float p2 = s_part[0][q][lane + 128] + s_part[1][q][lane + 128]
                 + s_part[2][q][lane + 128] + s_part[3][q][lane + 128];
        float p3 = s_part[0][q][lane + 192] + s_part[1][q][lane + 192]
                 + s_part[2][q][lane + 192] + s_part[3][q][lane + 192];
        float e0 = __builtin_amdgcn_exp2f(p0 * NL2E);
        float e1 = __builtin_amdgcn_exp2f(p1 * NL2E);
        float e2 = __builtin_amdgcn_exp2f(p2 * NL2E);
        float e3 = __builtin_amdgcn_exp2f(p3 * NL2E);
        s_alpha[q][lane]       = e0;
        s_alpha[q][lane + 64]  = e1;
        s_alpha[q][lane + 128] = e2;
        s_alpha[q][lane + 192] = e3;
        float s = (e0 + e1) + (e2 + e3);
        #pragma unroll
        for (int off = 32; off >= 1; off >>= 1) s += __shfl_xor(s, off);
        if (lane == 0) s_rsum[q] = 1.f / s;
    }
    __syncthreads();

    // ---- context: wave = (dgu, iqg); lane = (tl = lane>>4, il = lane&15)
    // thread covers 16 CONTIGUOUS t's (tl*16+step) -> alphas via ds_read_b128
    {
        const int iqg = __builtin_amdgcn_readfirstlane((tid >> 6) & 3);
        const int il  = lane & 15;
        const int tl  = lane >> 4;            // 0..3
        const int iq  = iqg * 16 + il;        // i-quad 0..63
        const int tbase = dgu * 64 + tl * 16;

        // register-block the 16 alphas per q (4x ds_read_b128 each)
        f32x4 al[QT][4];
        #pragma unroll
        for (int q = 0; q < QT; q++)
            #pragma unroll
            for (int c = 0; c < 4; c++)
                al[q][c] = *(const f32x4*)&s_alpha[q][tbase + c * 4];

        f32x4 ctx4[QT] = {};
        const float* kp0 = keys + ((size_t)b * TH + tbase) * DIN + iq * 4;

        #pragma unroll
        for (int step = 0; step < 16; step++) {
            f32x4 key4 = *(const f32x4*)(kp0 + (size_t)step * DIN);
            #pragma unroll
            for (int q = 0; q < QT; q++)
                ctx4[q] += key4 * al[q][step >> 2][step & 3];
        }

        // reduce across tl: lanes {l, l^16, l^32, l^48} hold same iq
        #pragma unroll
        for (int q = 0; q < QT; q++) {
            #pragma unroll
            for (int k = 0; k < 4; k++) {
                ctx4[q][k] += __shfl_xor(ctx4[q][k], 16);
                ctx4[q][k] += __shfl_xor(ctx4[q][k], 32);
            }
        }
        if (tl == 0) {
            #pragma unroll
            for (int q = 0; q < QT; q++)
                *(f32x4*)&s_part[dgu][q][iq * 4] = ctx4[q];
        }
    }
    __syncthreads();

    // ---- final reduce + normalize + store; all 1024 threads, 1 elem each ----
    {
        const int q = tid >> 8, ii = tid & 255;
        float s = s_part[0][q][ii] + s_part[1][q][ii]
                + s_part[2][q][ii] + s_part[3][q][ii];
        out[(size_t)(b * TQn + q0 + q) * DIN + ii] = s * s_rsum[q];
    }
}

// ---------------------------------------------------------------------------
extern "C" void kernel_launch(void* const* d_in, const int* in_sizes, int n_in,
                              void* d_out, int out_size, void* d_ws, size_t ws_size,
                              hipStream_t stream) {
    (void)in_sizes; (void)n_in; (void)out_size; (void)ws_size;
    const float* keys  = (const float*)d_in[0];  // [32*256][256]
    const float* state = (const float*)d_in[1];  // [32*64][256]
    const float* w1    = (const float*)d_in[2];  // [256][256]
    const float* w2    = (const float*)d_in[3];  // [256][256]
    const float* v     = (const float*)d_in[4];  // [256]
    float* out = (float*)d_out;                  // [2048][256]

    float* ktp = (float*)d_ws;                         // Ktp packed: 8 MB
    float* qp  = ktp + (size_t)BATCH * DD * TH;        // Pq: 2 MB

    hipLaunchKernelGGL(proj_kernel, dim3(640), dim3(256), 0, stream,
                       keys, state, w1, w2, ktp, qp);
    hipLaunchKernelGGL(attn_kernel, dim3(BATCH * (TQn / QT)), dim3(1024), 0, stream,
                       keys, v, ktp, qp, out);
}

// Round 10
// 103.647 us; speedup vs baseline: 1.0517x; 1.0517x over previous
//
#include <hip/hip_runtime.h>
#include <math.h>

#define BATCH 32
#define TH    256
#define TQn   64
#define DIN   256
#define DD    256   // INTERNAL
#define QT    4     // q's per attn block
#define E2C   2.885390081777927f   // 2*log2(e): exp(2x) == exp2(x*E2C)
#define NL2E  -2.8853900817779268f // -2*log2(e) for unshifted softmax exp2

typedef __attribute__((ext_vector_type(8)))  short bf16x8;   // 8 bf16 = 4 VGPRs
typedef __attribute__((ext_vector_type(16))) float floatx16;
typedef __attribute__((ext_vector_type(4)))  float f32x4;

// exp2(E2C*x) clamped to 2^30: den=1+P*K <= 2^60+1, pair product d0*d1 <= 2^121
// finite without per-element clamps. Clamp engages only at |proj| > 10.4 sigma.
__device__ __forceinline__ float eclamp(float x) {
    return __builtin_amdgcn_exp2f(fminf(x * E2C, 30.f));
}

// 2-term bf16 expansion of two floats, packed as (e0 low half | e1 high half).
__device__ __forceinline__ void split2(float x0, float x1, unsigned& hi, unsigned& lo) {
    unsigned u0 = __float_as_uint(x0), u1 = __float_as_uint(x1);
    unsigned h0 = u0 & 0xFFFF0000u,   h1 = u1 & 0xFFFF0000u;
    float r0 = x0 - __uint_as_float(h0);
    float r1 = x1 - __uint_as_float(h1);
    hi = (u0 >> 16) | h1;
    lo = (__float_as_uint(r0) >> 16) | (__float_as_uint(r1) & 0xFFFF0000u);
}

__device__ __forceinline__ void split8(float4 f0, float4 f1, uint4& hi, uint4& lo) {
    split2(f0.x, f0.y, hi.x, lo.x);
    split2(f0.z, f0.w, hi.y, lo.y);
    split2(f1.x, f1.y, hi.z, lo.z);
    split2(f1.z, f1.w, hi.w, lo.w);
}

// ---------------------------------------------------------------------------
// Kernel 1: projections via bf16-split MFMA (3x mfma_f32_32x32x16_bf16).
// Epilogue stores exp2c(proj):
//   Ktp packed: Ktp[b][d>>2][t][d&3]  (LDS transpose; attn reads dwordx4)
//   Pq[r][d]   (row-major; attn reads via uniform s_load)
// ---------------------------------------------------------------------------
#define REG4  65                    // uint4 per region (64 + 1 pad)
#define WOFF  (16 * REG4)           // W base in uint4 units
#define TSTR  68                    // transpose LDS stride (17*16B rows)
__global__ __launch_bounds__(256, 4)
void proj_kernel(const float* __restrict__ keys,
                 const float* __restrict__ state,
                 const float* __restrict__ w1,
                 const float* __restrict__ w2,
                 float* __restrict__ ktp,
                 float* __restrict__ qpo)
{
    __shared__ uint4 lds4[2 * 16 * REG4];   // 32.5 KB (reused for transpose)

    const int bid = blockIdx.x;
    const int tid = threadIdx.x;

    const float* X;
    const float* W;
    int m0, n0;
    bool is_kp;
    if (bid < 512) {
        is_kp = true;
        m0 = (bid >> 2) * 64;
        n0 = (bid & 3) * 64;
        X = keys; W = w1;
    } else {
        is_kp = false;
        int lb = bid - 512;
        m0 = (lb >> 2) * 64;
        n0 = (lb & 3) * 64;
        X = state; W = w2;
    }

    const int w    = tid >> 6;        // wave 0..3
    const int l    = tid & 63;
    const int mt   = w >> 1;          // m half-tile
    const int nt   = w & 1;           // n half-tile
    const int srow = tid >> 3;        // 0..31
    const int kg   = tid & 7;         // 0..7
    const int s_s  = kg >> 1;         // k-step 0..3
    const int lidx = (srow & 31) + 32 * (kg & 1);

    floatx16 acc = {};

    for (int k0 = 0; k0 < DIN; k0 += 64) {
        #pragma unroll
        for (int hrow = 0; hrow < 2; hrow++) {
            int m = srow + hrow * 32;
            const float* px = X + (size_t)(m0 + m) * DIN + k0 + kg * 8;
            uint4 hi, lo;
            split8(*(const float4*)px, *(const float4*)(px + 4), hi, lo);
            int g = m >> 5;
            lds4[((0 * 2 + g) * 4 + s_s) * REG4 + lidx] = hi;
            lds4[((2 + g) * 4 + s_s) * REG4 + lidx] = lo;
            const float* pw = W + (size_t)(n0 + m) * DIN + k0 + kg * 8;
            split8(*(const float4*)pw, *(const float4*)(pw + 4), hi, lo);
            lds4[WOFF + ((0 * 2 + g) * 4 + s_s) * REG4 + lidx] = hi;
            lds4[WOFF + ((2 + g) * 4 + s_s) * REG4 + lidx] = lo;
        }
        __syncthreads();

        #pragma unroll
        for (int s = 0; s < 4; s++) {
            uint4 ahr = lds4[((0 * 2 + mt) * 4 + s) * REG4 + l];
            uint4 alr = lds4[((2 + mt) * 4 + s) * REG4 + l];
            uint4 bhr = lds4[WOFF + ((0 * 2 + nt) * 4 + s) * REG4 + l];
            uint4 blr = lds4[WOFF + ((2 + nt) * 4 + s) * REG4 + l];
            bf16x8 ah = __builtin_bit_cast(bf16x8, ahr);
            bf16x8 al = __builtin_bit_cast(bf16x8, alr);
            bf16x8 bh = __builtin_bit_cast(bf16x8, bhr);
            bf16x8 bl = __builtin_bit_cast(bf16x8, blr);
            acc = __builtin_amdgcn_mfma_f32_32x32x16_bf16(ah, bh, acc, 0, 0, 0);
            acc = __builtin_amdgcn_mfma_f32_32x32x16_bf16(al, bh, acc, 0, 0, 0);
            acc = __builtin_amdgcn_mfma_f32_32x32x16_bf16(ah, bl, acc, 0, 0, 0);
        }
        __syncthreads();
    }

    // C/D map: col=l&31 (n=d), row=(r&3)+8*(r>>2)+4*(l>>5) (m=t/row)
    const int col = l & 31;
    const int hl  = l >> 5;
    if (is_kp) {
        // ---- transpose tile through LDS to d-packed layout ----
        float* sT = (float*)lds4;            // sT[t_local][d_local], stride TSTR
        const int d_local = nt * 32 + col;
        #pragma unroll
        for (int r = 0; r < 16; r++) {
            int t_local = mt * 32 + 4 * hl + 8 * (r >> 2) + (r & 3);
            sT[t_local * TSTR + d_local] = eclamp(acc[r]);
        }
        __syncthreads();
        const int b  = m0 >> 8;
        const int t0 = m0 & 255;
        float4* dst4 = (float4*)ktp;
        #pragma unroll
        for (int p = 0; p < 4; p++) {
            int dp_local = w * 4 + p;                 // 0..15
            float4 v4 = *(float4*)&sT[l * TSTR + dp_local * 4];
            dst4[(size_t)(b * 64 + (n0 >> 2) + dp_local) * 256 + t0 + l] = v4;
        }
    } else {
        const int d = n0 + nt * 32 + col;
        #pragma unroll
        for (int r = 0; r < 16; r++) {
            int row = (r & 3) + 8 * (r >> 2) + 4 * hl;
            qpo[(size_t)(m0 + mt * 32 + row) * DD + d] = eclamp(acc[r]);
        }
    }
}

// ---------------------------------------------------------------------------
// Kernel 2: fused scores + softmax + context — R7 structure (best measured)
// with the max-pass removed from softmax (|score| <= 2*sum|v| ~ 26 worst
// case, e^26 fp32-finite; validated in R8 at absmax 1.95e-3).
// Score: T(q,t) = sum_d v_d / (1 + Pq[q,d]*Kt[d,t]); softmax input = -2T;
//   Pq/v via wave-uniform s_load; kv 4-deep batched prefetch;
//   pair-combine rational (1 rcp / 2 d).
// Context: thread = (i-quad, t-chunk); f32x4 FMA, shfl_xor reduce, x4 stores.
// ---------------------------------------------------------------------------
__global__ __launch_bounds__(1024, 8)
void attn_kernel(const float* __restrict__ keys,
                 const float* __restrict__ vvec,
                 const float* __restrict__ ktp,
                 const float* __restrict__ qp,
                 float* __restrict__ out)
{
    __shared__ float s_part[4][QT][TH];   // 16 KB: score partials, then ctx partials
    __shared__ float s_alpha[QT][TH];     // 4 KB
    __shared__ float s_rsum[QT];

    const int bid  = blockIdx.x;
    const int b    = bid & 31;            // bid%8 == b%8 -> XCD-local batch
    const int q0   = (bid >> 5) * QT;
    const int tid  = threadIdx.x;
    const int t    = tid & 255;
    const int dgu  = __builtin_amdgcn_readfirstlane(tid >> 8);  // quarter, uniform
    const int lane = tid & 63;
    const int wv   = tid >> 6;

    // ---- scores (this quarter's 64 d's = 16 packed quads) ----
    float acc[QT];
    #pragma unroll
    for (int q = 0; q < QT; q++) acc[q] = 0.f;

    const float4* kb4 = (const float4*)ktp + ((size_t)(b * 64 + dgu * 16) * 256 + t);
    const float* pqr0 = qp + (size_t)(b * TQn + q0 + 0) * DD + dgu * 64;
    const float* pqr1 = qp + (size_t)(b * TQn + q0 + 1) * DD + dgu * 64;
    const float* pqr2 = qp + (size_t)(b * TQn + q0 + 2) * DD + dgu * 64;
    const float* pqr3 = qp + (size_t)(b * TQn + q0 + 3) * DD + dgu * 64;
    const float* vvp  = vvec + dgu * 64;

    float4 kv0 = kb4[0 * 256], kv1 = kb4[1 * 256],
           kv2 = kb4[2 * 256], kv3 = kb4[3 * 256];

    #pragma unroll
    for (int c = 0; c < 4; c++) {
        float4 n0v, n1v, n2v, n3v;
        if (c < 3) {
            const float4* p = kb4 + (size_t)(c + 1) * 4 * 256;
            n0v = p[0 * 256]; n1v = p[1 * 256];
            n2v = p[2 * 256]; n3v = p[3 * 256];
        }
        #pragma unroll
        for (int u = 0; u < 4; u++) {
            const int dp = c * 4 + u;
            float4 kv = (u == 0) ? kv0 : (u == 1) ? kv1 : (u == 2) ? kv2 : kv3;
            const float v0 = vvp[dp * 4 + 0], v1 = vvp[dp * 4 + 1];
            const float v2 = vvp[dp * 4 + 2], v3 = vvp[dp * 4 + 3];
            const float* pqr[QT] = {pqr0, pqr1, pqr2, pqr3};
            #pragma unroll
            for (int q = 0; q < QT; q++) {
                const float* pr = pqr[q];
                float d0 = fmaf(pr[dp * 4 + 0], kv.x, 1.f);
                float d1 = fmaf(pr[dp * 4 + 1], kv.y, 1.f);
                float n01 = fmaf(v1, d0, v0 * d1);
                acc[q] = fmaf(n01, __builtin_amdgcn_rcpf(d0 * d1), acc[q]);
                float d2 = fmaf(pr[dp * 4 + 2], kv.z, 1.f);
                float d3 = fmaf(pr[dp * 4 + 3], kv.w, 1.f);
                float n23 = fmaf(v3, d2, v2 * d3);
                acc[q] = fmaf(n23, __builtin_amdgcn_rcpf(d2 * d3), acc[q]);
            }
        }
        if (c < 3) { kv0 = n0v; kv1 = n1v; kv2 = n2v; kv3 = n3v; }
    }

    #pragma unroll
    for (int q = 0; q < QT; q++) s_part[dgu][q][t] = acc[q];
    __syncthreads();

    // ---- softmax over t=256, no max shift; wave wv (<QT) handles q=wv ----
    if (wv < QT) {
        const int q = wv;
        float p0 = s_part[0][q][lane]       + s_part[1][q][lane]
                 + s_part[2][q][lane]       + s_part[3][q][lane];
        float p1 = s_part[0][q][lane + 64]  + s_part[1][q][lane + 64]
                 + s_part[2][q][lane + 64]  + s_part[3][q][lane + 64];
        float p2 = s_part[0][q][lane + 128] + s_part[1][q][lane + 128]
                 + s_part[2][q][lane + 128] + s_part[3][q][lane + 128];
        float p3 = s_part[0][q][lane + 192] + s_part[1][q][lane + 192]
                 + s_part[2][q][lane + 192] + s_part[3][q][lane + 192];
        float e0 = __builtin_amdgcn_exp2f(p0 * NL2E);
        float e1 = __builtin_amdgcn_exp2f(p1 * NL2E);
        float e2 = __builtin_amdgcn_exp2f(p2 * NL2E);
        float e3 = __builtin_amdgcn_exp2f(p3 * NL2E);
        s_alpha[q][lane]       = e0;
        s_alpha[q][lane + 64]  = e1;
        s_alpha[q][lane + 128] = e2;
        s_alpha[q][lane + 192] = e3;
        float s = (e0 + e1) + (e2 + e3);
        #pragma unroll
        for (int off = 32; off >= 1; off >>= 1) s += __shfl_xor(s, off);
        if (lane == 0) s_rsum[q] = 1.f / s;
    }
    __syncthreads();

    // ---- context: wave = (t-quarter dgu, i-quad group iqg); lane = (tl, il)
    {
        const int iqg = __builtin_amdgcn_readfirstlane((tid >> 6) & 3);
        const int il  = lane & 15;
        const int tl  = lane >> 4;            // 0..3 (t sub-offset)
        const int iq  = iqg * 16 + il;        // i-quad 0..63

        f32x4 ctx4[QT] = {};
        const float* kp0 = keys + ((size_t)b * TH + dgu * 64 + tl) * DIN + iq * 4;

        #pragma unroll 4
        for (int step = 0; step < 16; step++) {
            f32x4 key4 = *(const f32x4*)(kp0 + (size_t)step * 4 * DIN);
            const int ta = dgu * 64 + step * 4 + tl;
            #pragma unroll
            for (int q = 0; q < QT; q++)
                ctx4[q] += key4 * s_alpha[q][ta];
        }

        // reduce across tl: lanes {l, l^16, l^32, l^48} hold same iq
        #pragma unroll
        for (int q = 0; q < QT; q++) {
            #pragma unroll
            for (int k = 0; k < 4; k++) {
                ctx4[q][k] += __shfl_xor(ctx4[q][k], 16);
                ctx4[q][k] += __shfl_xor(ctx4[q][k], 32);
            }
        }
        if (tl == 0) {
            #pragma unroll
            for (int q = 0; q < QT; q++)
                *(f32x4*)&s_part[dgu][q][iq * 4] = ctx4[q];
        }
    }
    __syncthreads();

    // ---- final reduce + normalize + store (dwordx4) ----
    if (tid < 256) {
        const int q = tid >> 6, iqf = tid & 63;
        f32x4 s = *(const f32x4*)&s_part[0][q][iqf * 4];
        s += *(const f32x4*)&s_part[1][q][iqf * 4];
        s += *(const f32x4*)&s_part[2][q][iqf * 4];
        s += *(const f32x4*)&s_part[3][q][iqf * 4];
        s *= s_rsum[q];
        *(f32x4*)&out[(size_t)(b * TQn + q0 + q) * DIN + iqf * 4] = s;
    }
}

// ---------------------------------------------------------------------------
extern "C" void kernel_launch(void* const* d_in, const int* in_sizes, int n_in,
                              void* d_out, int out_size, void* d_ws, size_t ws_size,
                              hipStream_t stream) {
    (void)in_sizes; (void)n_in; (void)out_size; (void)ws_size;
    const float* keys  = (const float*)d_in[0];  // [32*256][256]
    const float* state = (const float*)d_in[1];  // [32*64][256]
    const float* w1    = (const float*)d_in[2];  // [256][256]
    const float* w2    = (const float*)d_in[3];  // [256][256]
    const float* v     = (const float*)d_in[4];  // [256]
    float* out = (float*)d_out;                  // [2048][256]

    float* ktp = (float*)d_ws;                         // Ktp packed: 8 MB
    float* qp  = ktp + (size_t)BATCH * DD * TH;        // Pq: 2 MB

    hipLaunchKernelGGL(proj_kernel, dim3(640), dim3(256), 0, stream,
                       keys, state, w1, w2, ktp, qp);
    hipLaunchKernelGGL(attn_kernel, dim3(BATCH * (TQn / QT)), dim3(1024), 0, stream,
                       keys, v, ktp, qp, out);
}

// Round 11
// 103.098 us; speedup vs baseline: 1.0573x; 1.0053x over previous
//
#include <hip/hip_runtime.h>
#include <math.h>

#define BATCH 32
#define TH    256
#define TQn   64
#define DIN   256
#define DD    256   // INTERNAL
#define QT    4     // q's per attn block
#define E2C   2.885390081777927f   // 2*log2(e): exp(2x) == exp2(x*E2C)
#define NL2E  -2.8853900817779268f // -2*log2(e) for unshifted softmax exp2

typedef __attribute__((ext_vector_type(8)))  short bf16x8;   // 8 bf16 = 4 VGPRs
typedef __attribute__((ext_vector_type(16))) float floatx16;
typedef __attribute__((ext_vector_type(4)))  float f32x4;

// exp2(E2C*x) clamped to 2^15: den=1+P*K <= 2^30+1, pair product <= 2^61,
// quad product <= 2^122 — finite through the QUAD-tree rational combine with
// no per-element clamps. Clamp error: sigma changes by <= 2^-30 (saturated
// tanh tail) — ~1e-9 per element, invisible at the 7e-3 threshold.
__device__ __forceinline__ float eclamp(float x) {
    return __builtin_amdgcn_exp2f(fminf(x * E2C, 15.f));
}

// 2-term bf16 expansion of two floats, packed as (e0 low half | e1 high half).
__device__ __forceinline__ void split2(float x0, float x1, unsigned& hi, unsigned& lo) {
    unsigned u0 = __float_as_uint(x0), u1 = __float_as_uint(x1);
    unsigned h0 = u0 & 0xFFFF0000u,   h1 = u1 & 0xFFFF0000u;
    float r0 = x0 - __uint_as_float(h0);
    float r1 = x1 - __uint_as_float(h1);
    hi = (u0 >> 16) | h1;
    lo = (__float_as_uint(r0) >> 16) | (__float_as_uint(r1) & 0xFFFF0000u);
}

__device__ __forceinline__ void split8(float4 f0, float4 f1, uint4& hi, uint4& lo) {
    split2(f0.x, f0.y, hi.x, lo.x);
    split2(f0.z, f0.w, hi.y, lo.y);
    split2(f1.x, f1.y, hi.z, lo.z);
    split2(f1.z, f1.w, hi.w, lo.w);
}

// ---------------------------------------------------------------------------
// Kernel 1: projections via bf16-split MFMA (3x mfma_f32_32x32x16_bf16).
// Epilogue stores exp2c(proj):
//   Ktp packed: Ktp[b][d>>2][t][d&3]  (LDS transpose; attn reads dwordx4)
//   Pq[r][d]   (row-major; attn reads via uniform s_load)
// ---------------------------------------------------------------------------
#define REG4  65                    // uint4 per region (64 + 1 pad)
#define WOFF  (16 * REG4)           // W base in uint4 units
#define TSTR  68                    // transpose LDS stride (17*16B rows)
__global__ __launch_bounds__(256, 4)
void proj_kernel(const float* __restrict__ keys,
                 const float* __restrict__ state,
                 const float* __restrict__ w1,
                 const float* __restrict__ w2,
                 float* __restrict__ ktp,
                 float* __restrict__ qpo)
{
    __shared__ uint4 lds4[2 * 16 * REG4];   // 32.5 KB (reused for transpose)

    const int bid = blockIdx.x;
    const int tid = threadIdx.x;

    const float* X;
    const float* W;
    int m0, n0;
    bool is_kp;
    if (bid < 512) {
        is_kp = true;
        m0 = (bid >> 2) * 64;
        n0 = (bid & 3) * 64;
        X = keys; W = w1;
    } else {
        is_kp = false;
        int lb = bid - 512;
        m0 = (lb >> 2) * 64;
        n0 = (lb & 3) * 64;
        X = state; W = w2;
    }

    const int w    = tid >> 6;        // wave 0..3
    const int l    = tid & 63;
    const int mt   = w >> 1;          // m half-tile
    const int nt   = w & 1;           // n half-tile
    const int srow = tid >> 3;        // 0..31
    const int kg   = tid & 7;         // 0..7
    const int s_s  = kg >> 1;         // k-step 0..3
    const int lidx = (srow & 31) + 32 * (kg & 1);

    floatx16 acc = {};

    for (int k0 = 0; k0 < DIN; k0 += 64) {
        #pragma unroll
        for (int hrow = 0; hrow < 2; hrow++) {
            int m = srow + hrow * 32;
            const float* px = X + (size_t)(m0 + m) * DIN + k0 + kg * 8;
            uint4 hi, lo;
            split8(*(const float4*)px, *(const float4*)(px + 4), hi, lo);
            int g = m >> 5;
            lds4[((0 * 2 + g) * 4 + s_s) * REG4 + lidx] = hi;
            lds4[((2 + g) * 4 + s_s) * REG4 + lidx] = lo;
            const float* pw = W + (size_t)(n0 + m) * DIN + k0 + kg * 8;
            split8(*(const float4*)pw, *(const float4*)(pw + 4), hi, lo);
            lds4[WOFF + ((0 * 2 + g) * 4 + s_s) * REG4 + lidx] = hi;
            lds4[WOFF + ((2 + g) * 4 + s_s) * REG4 + lidx] = lo;
        }
        __syncthreads();

        #pragma unroll
        for (int s = 0; s < 4; s++) {
            uint4 ahr = lds4[((0 * 2 + mt) * 4 + s) * REG4 + l];
            uint4 alr = lds4[((2 + mt) * 4 + s) * REG4 + l];
            uint4 bhr = lds4[WOFF + ((0 * 2 + nt) * 4 + s) * REG4 + l];
            uint4 blr = lds4[WOFF + ((2 + nt) * 4 + s) * REG4 + l];
            bf16x8 ah = __builtin_bit_cast(bf16x8, ahr);
            bf16x8 al = __builtin_bit_cast(bf16x8, alr);
            bf16x8 bh = __builtin_bit_cast(bf16x8, bhr);
            bf16x8 bl = __builtin_bit_cast(bf16x8, blr);
            acc = __builtin_amdgcn_mfma_f32_32x32x16_bf16(ah, bh, acc, 0, 0, 0);
            acc = __builtin_amdgcn_mfma_f32_32x32x16_bf16(al, bh, acc, 0, 0, 0);
            acc = __builtin_amdgcn_mfma_f32_32x32x16_bf16(ah, bl, acc, 0, 0, 0);
        }
        __syncthreads();
    }

    // C/D map: col=l&31 (n=d), row=(r&3)+8*(r>>2)+4*(l>>5) (m=t/row)
    const int col = l & 31;
    const int hl  = l >> 5;
    if (is_kp) {
        // ---- transpose tile through LDS to d-packed layout ----
        float* sT = (float*)lds4;            // sT[t_local][d_local], stride TSTR
        const int d_local = nt * 32 + col;
        #pragma unroll
        for (int r = 0; r < 16; r++) {
            int t_local = mt * 32 + 4 * hl + 8 * (r >> 2) + (r & 3);
            sT[t_local * TSTR + d_local] = eclamp(acc[r]);
        }
        __syncthreads();
        const int b  = m0 >> 8;
        const int t0 = m0 & 255;
        float4* dst4 = (float4*)ktp;
        #pragma unroll
        for (int p = 0; p < 4; p++) {
            int dp_local = w * 4 + p;                 // 0..15
            float4 v4 = *(float4*)&sT[l * TSTR + dp_local * 4];
            dst4[(size_t)(b * 64 + (n0 >> 2) + dp_local) * 256 + t0 + l] = v4;
        }
    } else {
        const int d = n0 + nt * 32 + col;
        #pragma unroll
        for (int r = 0; r < 16; r++) {
            int row = (r & 3) + 8 * (r >> 2) + 4 * hl;
            qpo[(size_t)(m0 + mt * 32 + row) * DD + d] = eclamp(acc[r]);
        }
    }
}

// ---------------------------------------------------------------------------
// Kernel 2: fused scores + softmax + context — R7/R10 structure with
// QUAD-tree rational combine (1 rcp / 4 d's; eclamp(15) makes it
// overflow-safe with zero per-element clamps; numerics validated in R4).
// Score: T(q,t) = sum_d v_d / (1 + Pq[q,d]*Kt[d,t]); softmax input = -2T;
//   Pq/v via wave-uniform s_load; kv 4-deep batched prefetch.
// Softmax without max-shift (R8/R10-validated). Context: f32x4 FMA,
// shfl_xor reduce, dwordx4 stores.
// ---------------------------------------------------------------------------
__global__ __launch_bounds__(1024, 8)
void attn_kernel(const float* __restrict__ keys,
                 const float* __restrict__ vvec,
                 const float* __restrict__ ktp,
                 const float* __restrict__ qp,
                 float* __restrict__ out)
{
    __shared__ float s_part[4][QT][TH];   // 16 KB: score partials, then ctx partials
    __shared__ float s_alpha[QT][TH];     // 4 KB
    __shared__ float s_rsum[QT];

    const int bid  = blockIdx.x;
    const int b    = bid & 31;            // bid%8 == b%8 -> XCD-local batch
    const int q0   = (bid >> 5) * QT;
    const int tid  = threadIdx.x;
    const int t    = tid & 255;
    const int dgu  = __builtin_amdgcn_readfirstlane(tid >> 8);  // quarter, uniform
    const int lane = tid & 63;
    const int wv   = tid >> 6;

    // ---- scores (this quarter's 64 d's = 16 packed quads) ----
    float acc[QT];
    #pragma unroll
    for (int q = 0; q < QT; q++) acc[q] = 0.f;

    const float4* kb4 = (const float4*)ktp + ((size_t)(b * 64 + dgu * 16) * 256 + t);
    const float* pqr0 = qp + (size_t)(b * TQn + q0 + 0) * DD + dgu * 64;
    const float* pqr1 = qp + (size_t)(b * TQn + q0 + 1) * DD + dgu * 64;
    const float* pqr2 = qp + (size_t)(b * TQn + q0 + 2) * DD + dgu * 64;
    const float* pqr3 = qp + (size_t)(b * TQn + q0 + 3) * DD + dgu * 64;
    const float* vvp  = vvec + dgu * 64;

    float4 kv0 = kb4[0 * 256], kv1 = kb4[1 * 256],
           kv2 = kb4[2 * 256], kv3 = kb4[3 * 256];

    #pragma unroll
    for (int c = 0; c < 4; c++) {
        float4 n0v, n1v, n2v, n3v;
        if (c < 3) {
            const float4* p = kb4 + (size_t)(c + 1) * 4 * 256;
            n0v = p[0 * 256]; n1v = p[1 * 256];
            n2v = p[2 * 256]; n3v = p[3 * 256];
        }
        #pragma unroll
        for (int u = 0; u < 4; u++) {
            const int dp = c * 4 + u;
            float4 kv = (u == 0) ? kv0 : (u == 1) ? kv1 : (u == 2) ? kv2 : kv3;
            const float v0 = vvp[dp * 4 + 0], v1 = vvp[dp * 4 + 1];
            const float v2 = vvp[dp * 4 + 2], v3 = vvp[dp * 4 + 3];
            const float* pqr[QT] = {pqr0, pqr1, pqr2, pqr3};
            #pragma unroll
            for (int q = 0; q < QT; q++) {
                const float* pr = pqr[q];
                float d0 = fmaf(pr[dp * 4 + 0], kv.x, 1.f);
                float d1 = fmaf(pr[dp * 4 + 1], kv.y, 1.f);
                float d2 = fmaf(pr[dp * 4 + 2], kv.z, 1.f);
                float d3 = fmaf(pr[dp * 4 + 3], kv.w, 1.f);
                // quad rational: sum v_j/d_j with ONE rcp (exact algebra)
                float n01 = fmaf(v1, d0, v0 * d1);
                float d01 = d0 * d1;
                float n23 = fmaf(v3, d2, v2 * d3);
                float d23 = d2 * d3;
                float num = fmaf(n23, d01, n01 * d23);
                float den = d01 * d23;
                acc[q] = fmaf(num, __builtin_amdgcn_rcpf(den), acc[q]);
            }
        }
        if (c < 3) { kv0 = n0v; kv1 = n1v; kv2 = n2v; kv3 = n3v; }
    }

    #pragma unroll
    for (int q = 0; q < QT; q++) s_part[dgu][q][t] = acc[q];
    __syncthreads();

    // ---- softmax over t=256, no max shift; wave wv (<QT) handles q=wv ----
    if (wv < QT) {
        const int q = wv;
        float p0 = s_part[0][q][lane]       + s_part[1][q][lane]
                 + s_part[2][q][lane]       + s_part[3][q][lane];
        float p1 = s_part[0][q][lane + 64]  + s_part[1][q][lane + 64]
                 + s_part[2][q][lane + 64]  + s_part[3][q][lane + 64];
        float p2 = s_part[0][q][lane + 128] + s_part[1][q][lane + 128]
                 + s_part[2][q][lane + 128] + s_part[3][q][lane + 128];
        float p3 = s_part[0][q][lane + 192] + s_part[1][q][lane + 192]
                 + s_part[2][q][lane + 192] + s_part[3][q][lane + 192];
        float e0 = __builtin_amdgcn_exp2f(p0 * NL2E);
        float e1 = __builtin_amdgcn_exp2f(p1 * NL2E);
        float e2 = __builtin_amdgcn_exp2f(p2 * NL2E);
        float e3 = __builtin_amdgcn_exp2f(p3 * NL2E);
        s_alpha[q][lane]       = e0;
        s_alpha[q][lane + 64]  = e1;
        s_alpha[q][lane + 128] = e2;
        s_alpha[q][lane + 192] = e3;
        float s = (e0 + e1) + (e2 + e3);
        #pragma unroll
        for (int off = 32; off >= 1; off >>= 1) s += __shfl_xor(s, off);
        if (lane == 0) s_rsum[q] = 1.f / s;
    }
    __syncthreads();

    // ---- context: wave = (t-quarter dgu, i-quad group iqg); lane = (tl, il)
    {
        const int iqg = __builtin_amdgcn_readfirstlane((tid >> 6) & 3);
        const int il  = lane & 15;
        const int tl  = lane >> 4;            // 0..3 (t sub-offset)
        const int iq  = iqg * 16 + il;        // i-quad 0..63

        f32x4 ctx4[QT] = {};
        const float* kp0 = keys + ((size_t)b * TH + dgu * 64 + tl) * DIN + iq * 4;

        #pragma unroll 4
        for (int step = 0; step < 16; step++) {
            f32x4 key4 = *(const f32x4*)(kp0 + (size_t)step * 4 * DIN);
            const int ta = dgu * 64 + step * 4 + tl;
            #pragma unroll
            for (int q = 0; q < QT; q++)
                ctx4[q] += key4 * s_alpha[q][ta];
        }

        // reduce across tl: lanes {l, l^16, l^32, l^48} hold same iq
        #pragma unroll
        for (int q = 0; q < QT; q++) {
            #pragma unroll
            for (int k = 0; k < 4; k++) {
                ctx4[q][k] += __shfl_xor(ctx4[q][k], 16);
                ctx4[q][k] += __shfl_xor(ctx4[q][k], 32);
            }
        }
        if (tl == 0) {
            #pragma unroll
            for (int q = 0; q < QT; q++)
                *(f32x4*)&s_part[dgu][q][iq * 4] = ctx4[q];
        }
    }
    __syncthreads();

    // ---- final reduce + normalize + store (dwordx4) ----
    if (tid < 256) {
        const int q = tid >> 6, iqf = tid & 63;
        f32x4 s = *(const f32x4*)&s_part[0][q][iqf * 4];
        s += *(const f32x4*)&s_part[1][q][iqf * 4];
        s += *(const f32x4*)&s_part[2][q][iqf * 4];
        s += *(const f32x4*)&s_part[3][q][iqf * 4];
        s *= s_rsum[q];
        *(f32x4*)&out[(size_t)(b * TQn + q0 + q) * DIN + iqf * 4] = s;
    }
}

// ---------------------------------------------------------------------------
extern "C" void kernel_launch(void* const* d_in, const int* in_sizes, int n_in,
                              void* d_out, int out_size, void* d_ws, size_t ws_size,
                              hipStream_t stream) {
    (void)in_sizes; (void)n_in; (void)out_size; (void)ws_size;
    const float* keys  = (const float*)d_in[0];  // [32*256][256]
    const float* state = (const float*)d_in[1];  // [32*64][256]
    const float* w1    = (const float*)d_in[2];  // [256][256]
    const float* w2    = (const float*)d_in[3];  // [256][256]
    const float* v     = (const float*)d_in[4];  // [256]
    float* out = (float*)d_out;                  // [2048][256]

    float* ktp = (float*)d_ws;                         // Ktp packed: 8 MB
    float* qp  = ktp + (size_t)BATCH * DD * TH;        // Pq: 2 MB

    hipLaunchKernelGGL(proj_kernel, dim3(640), dim3(256), 0, stream,
                       keys, state, w1, w2, ktp, qp);
    hipLaunchKernelGGL(attn_kernel, dim3(BATCH * (TQn / QT)), dim3(1024), 0, stream,
                       keys, v, ktp, qp, out);
}